// Round 8
// baseline (323.164 us; speedup 1.0000x reference)
//
#include <hip/hip_runtime.h>

#define CH 64
#define CSHIFT 11            // coarse bucket = dst >> 11
#define CNODES 2048          // nodes per coarse bucket
#define NC_MAX 64
#define CSTRIDE 36864        // coarse region stride (entries); mean 32768, +23 sigma
#define OSTRIDE 53248        // output region stride (entries); CSTRIDE + 2048*8 pad slack
#define CUR_PAD 16           // cursor padding: 16 ints = 64 B = own cache line
#define SCAT_CHUNK 8192      // edges per scatter block (256 thr, 32 iters)

typedef unsigned short ushort_t;
typedef unsigned int uint_t;
typedef short short8_t __attribute__((ext_vector_type(8)));
typedef float float4_t __attribute__((ext_vector_type(4)));

static __device__ __forceinline__ ushort_t f2bf(float x) {
    uint_t u = __float_as_uint(x);
    u = (u + 0x7FFFu + ((u >> 16) & 1u)) >> 16;   // RNE
    return (ushort_t)u;
}
static __device__ __forceinline__ float bflo(uint_t u) {
    return __uint_as_float(u << 16);
}
static __device__ __forceinline__ float bfhi(uint_t u) {
    return __uint_as_float(u & 0xFFFF0000u);
}

// ---------------- prep: 3 weight transposes + coarse cursors + B zero-row ----------------
__global__ __launch_bounds__(256) void prep_kernel(
    const float* __restrict__ W1, const float* __restrict__ W2, const float* __restrict__ W3,
    ushort_t* __restrict__ Wt1, ushort_t* __restrict__ Wt2, ushort_t* __restrict__ Wt3,
    int* __restrict__ cursor, ushort_t* __restrict__ hwbB_zrow)
{
    const int b = blockIdx.x;
    if (b == 3) {
        if (threadIdx.x < NC_MAX) cursor[threadIdx.x * CUR_PAD] = threadIdx.x * CSTRIDE;
        if (threadIdx.x < CH) hwbB_zrow[threadIdx.x] = 0;   // zero row N of buffer B
        return;
    }
    const float* W = (b == 0) ? W1 : (b == 1) ? W2 : W3;
    ushort_t* Wt   = (b == 0) ? Wt1 : (b == 1) ? Wt2 : Wt3;
    const int K    = (b == 0) ? 128 : 64;
    for (int i = threadIdx.x; i < K * CH; i += 256) {
        int n = i / K, k = i % K;
        Wt[i] = f2bf(W[(size_t)k * CH + n]);
    }
}

// ---------------- MFMA GEMM body: outb[r][64] = bf16( h[r][K] @ W[K][64] ), + zero row at r==n ----
template<int K, typename T>
static __device__ __forceinline__ void gemm_body(
    const T* __restrict__ h, const ushort_t* __restrict__ Wt,
    ushort_t* __restrict__ outb, int n, ushort_t* Hs, int blockRow)
{
    constexpr int LDH = K + 8;
    constexpr int C8  = K / 8;
    constexpr int KC  = K / 32;

    const int t    = threadIdx.x;
    const int lane = t & 63;
    const int wv   = t >> 6;
    const int l15  = lane & 15;
    const int quad = lane >> 4;
    const int row0 = blockRow * 128;

    short8_t bfrag[4][KC];
    #pragma unroll
    for (int nt = 0; nt < 4; ++nt)
        #pragma unroll
        for (int kc = 0; kc < KC; ++kc)
            bfrag[nt][kc] = *(const short8_t*)(Wt + (size_t)(nt * 16 + l15) * K + kc * 32 + quad * 8);

    for (int idx = t; idx < 128 * C8; idx += 256) {
        int r  = idx / C8;
        int c8 = idx % C8;
        int rg = row0 + r;
        short8_t v = (short8_t)0;
        if (rg < n) {
            if constexpr (sizeof(T) == 4) {
                const float* p = (const float*)h + (size_t)rg * K + c8 * 8;
                float4 f0 = *(const float4*)p;
                float4 f1 = *(const float4*)(p + 4);
                v[0] = (short)f2bf(f0.x); v[1] = (short)f2bf(f0.y);
                v[2] = (short)f2bf(f0.z); v[3] = (short)f2bf(f0.w);
                v[4] = (short)f2bf(f1.x); v[5] = (short)f2bf(f1.y);
                v[6] = (short)f2bf(f1.z); v[7] = (short)f2bf(f1.w);
            } else {
                v = *(const short8_t*)((const ushort_t*)h + (size_t)rg * K + c8 * 8);
            }
        }
        *(short8_t*)&Hs[r * LDH + c8 * 8] = v;
    }
    __syncthreads();

    float4_t acc[2][4];
    #pragma unroll
    for (int mi = 0; mi < 2; ++mi)
        #pragma unroll
        for (int nt = 0; nt < 4; ++nt)
            acc[mi][nt] = (float4_t)0.f;

    #pragma unroll
    for (int kc = 0; kc < KC; ++kc) {
        short8_t a0 = *(const short8_t*)&Hs[(wv * 32 +      l15) * LDH + kc * 32 + quad * 8];
        short8_t a1 = *(const short8_t*)&Hs[(wv * 32 + 16 + l15) * LDH + kc * 32 + quad * 8];
        #pragma unroll
        for (int nt = 0; nt < 4; ++nt) {
            acc[0][nt] = __builtin_amdgcn_mfma_f32_16x16x32_bf16(a0, bfrag[nt][kc], acc[0][nt], 0, 0, 0);
            acc[1][nt] = __builtin_amdgcn_mfma_f32_16x16x32_bf16(a1, bfrag[nt][kc], acc[1][nt], 0, 0, 0);
        }
    }

    #pragma unroll
    for (int mi = 0; mi < 2; ++mi) {
        #pragma unroll
        for (int r = 0; r < 4; ++r) {
            int row = row0 + wv * 32 + mi * 16 + quad * 4 + r;
            if (row <= n) {
                #pragma unroll
                for (int nt = 0; nt < 4; ++nt)
                    outb[(size_t)row * CH + nt * 16 + l15] = f2bf(acc[mi][nt][r]);
            }
        }
    }
}

// ---------------- fused layer-1 GEMM + coarse scatter (pass A) ----------------
// Scatter blocks: block-aggregated scatter into 49 coarse buckets (dst>>11) with
// fixed-stride regions (no hist/scan). Runs of ~167 edges per block per bucket
// -> full-line writes. packed = ((dst & 2047) << 17) | src   (src < 2^17).
__global__ __launch_bounds__(256) void gemm1_scat(
    const float* __restrict__ x, const ushort_t* __restrict__ Wt1,
    ushort_t* __restrict__ outb, int n,
    const int* __restrict__ esrc, const int* __restrict__ edst,
    int* __restrict__ cursor, int* __restrict__ bucketed, int E, int gemmGrid)
{
    __shared__ ushort_t Hs[128 * 136];
    if (blockIdx.x >= gemmGrid) {
        __shared__ int hist[NC_MAX];
        __shared__ int rbase[NC_MAX];
        __shared__ int lcur[NC_MAX];
        const int t = threadIdx.x;
        const int s = (blockIdx.x - gemmGrid) * SCAT_CHUNK;
        const int e = min(s + SCAT_CHUNK, E);

        if (t < NC_MAX) hist[t] = 0;
        __syncthreads();
        for (int i = s + t; i < e; i += 256)
            atomicAdd(&hist[edst[i] >> CSHIFT], 1);
        __syncthreads();
        if (t < NC_MAX) {
            int c = hist[t];
            rbase[t] = c ? atomicAdd(&cursor[t * CUR_PAD], c) : 0;
            lcur[t] = 0;
        }
        __syncthreads();
        for (int i = s + t; i < e; i += 256) {
            int d = edst[i];
            int cb = d >> CSHIFT;
            int p = atomicAdd(&lcur[cb], 1);
            int idx = rbase[cb] + p;
            if (idx < (cb + 1) * CSTRIDE)        // overflow guard (23 sigma slack)
                bucketed[idx] = ((d & (CNODES - 1)) << 17) | esrc[i];
        }
        return;
    }
    gemm_body<128, float>(x, Wt1, outb, n, Hs, blockIdx.x);
}

// ---------------- pass B: per-coarse-bucket counting sort -> padded per-node segments ----
// One block (1024 thr) per coarse bucket of ~33K edges / 2048 nodes. All writes land in
// the block's own 208KB output region -> L2-composed full lines. Entries pre-scaled by 8.
__global__ __launch_bounds__(1024) void node_sort2(
    const int* __restrict__ bucketed, const int* __restrict__ cursor,
    int* __restrict__ sorted_src, int2* __restrict__ seg, int N, int zrow)
{
    __shared__ int cnt[CNODES];
    __shared__ int cur[CNODES];
    __shared__ int tsum[1024];
    const int bk    = blockIdx.x;
    const int t     = threadIdx.x;
    const int cbase = bk * CSTRIDE;
    const int obase = bk * OSTRIDE;

    int count = cursor[bk * CUR_PAD] - cbase;
    if (count > CSTRIDE) count = CSTRIDE;

    cnt[t] = 0; cnt[t + 1024] = 0;
    __syncthreads();

    for (int i = t; i < count; i += 1024)
        atomicAdd(&cnt[((unsigned)bucketed[cbase + i]) >> 17], 1);
    __syncthreads();

    int c0 = cnt[2 * t], c1 = cnt[2 * t + 1];
    int p0 = (c0 + 7) & ~7, p1 = (c1 + 7) & ~7;
    int local = p0 + p1;
    tsum[t] = local;
    __syncthreads();
    for (int off = 1; off < 1024; off <<= 1) {
        int v = (t >= off) ? tsum[t - off] : 0;
        __syncthreads();
        tsum[t] += v;
        __syncthreads();
    }
    int excl = tsum[t] - local;

    cur[2 * t]     = excl;
    cur[2 * t + 1] = excl + p0;
    const int zv = zrow << 3;
    {
        int node = bk * CNODES + 2 * t;
        if (node < N) {
            seg[node] = make_int2(obase + excl, p0);
            for (int k = c0; k < p0; ++k) sorted_src[obase + excl + k] = zv;
        }
        int node1 = node + 1;
        if (node1 < N) {
            seg[node1] = make_int2(obase + excl + p0, p1);
            for (int k = c1; k < p1; ++k) sorted_src[obase + excl + p0 + k] = zv;
        }
    }
    __syncthreads();

    for (int i = t; i < count; i += 1024) {
        int e = bucketed[cbase + i];
        int d = ((unsigned)e) >> 17;
        int pos = atomicAdd(&cur[d], 1);
        sorted_src[obase + pos] = (e & 0x1FFFF) << 3;
    }
}

// ---------------- shared aggregate core: one wave aggregates one node ----------------
static __device__ __forceinline__ void agg_core(
    const uint4* __restrict__ hw4, const int* __restrict__ sorted_src,
    int base, int pc, int g, int c,
    float& a0, float& a1, float& a2, float& a3,
    float& a4, float& a5, float& a6, float& a7)
{
    const int* sp = sorted_src + base;
    int u = 0;
    for (; u + 16 <= pc; u += 16) {
        int r0 = sp[u +     g];
        int r1 = sp[u + 8 + g];
        uint4 v0 = hw4[(size_t)(r0 + c)];
        uint4 v1 = hw4[(size_t)(r1 + c)];
        a0 += bflo(v0.x); a1 += bfhi(v0.x); a2 += bflo(v0.y); a3 += bfhi(v0.y);
        a4 += bflo(v0.z); a5 += bfhi(v0.z); a6 += bflo(v0.w); a7 += bfhi(v0.w);
        a0 += bflo(v1.x); a1 += bfhi(v1.x); a2 += bflo(v1.y); a3 += bfhi(v1.y);
        a4 += bflo(v1.z); a5 += bfhi(v1.z); a6 += bflo(v1.w); a7 += bfhi(v1.w);
    }
    if (u < pc) {
        int r0 = sp[u + g];
        uint4 v0 = hw4[(size_t)(r0 + c)];
        a0 += bflo(v0.x); a1 += bfhi(v0.x); a2 += bflo(v0.y); a3 += bfhi(v0.y);
        a4 += bflo(v0.z); a5 += bfhi(v0.z); a6 += bflo(v0.w); a7 += bfhi(v0.w);
    }

    a0 += __shfl_xor(a0, 8);  a1 += __shfl_xor(a1, 8);
    a2 += __shfl_xor(a2, 8);  a3 += __shfl_xor(a3, 8);
    a4 += __shfl_xor(a4, 8);  a5 += __shfl_xor(a5, 8);
    a6 += __shfl_xor(a6, 8);  a7 += __shfl_xor(a7, 8);
    a0 += __shfl_xor(a0, 16); a1 += __shfl_xor(a1, 16);
    a2 += __shfl_xor(a2, 16); a3 += __shfl_xor(a3, 16);
    a4 += __shfl_xor(a4, 16); a5 += __shfl_xor(a5, 16);
    a6 += __shfl_xor(a6, 16); a7 += __shfl_xor(a7, 16);
    a0 += __shfl_xor(a0, 32); a1 += __shfl_xor(a1, 32);
    a2 += __shfl_xor(a2, 32); a3 += __shfl_xor(a3, 32);
    a4 += __shfl_xor(a4, 32); a5 += __shfl_xor(a5, 32);
    a6 += __shfl_xor(a6, 32); a7 += __shfl_xor(a7, 32);
}

// ---------------- fused aggregate + relu + 64x64 GEMM (layers 1->2, 2->3) ----------------
__global__ __launch_bounds__(256) void agg_gemm(
    const ushort_t* __restrict__ hwb_in, const int* __restrict__ sorted_src,
    const int2* __restrict__ seg, const float* __restrict__ bias,
    const ushort_t* __restrict__ Wt, ushort_t* __restrict__ outb, int N)
{
    __shared__ ushort_t Hs[4 * 72];          // 4 rows x (64+8) bf16
    const int t    = threadIdx.x;
    const int lane = t & 63;
    const int wv   = t >> 6;
    const int node = blockIdx.x * 4 + wv;
    const int g    = lane >> 3;
    const int c    = lane & 7;
    const uint4* hw4 = (const uint4*)hwb_in;

    int base = 0, pc = 0;
    if (node < N) {
        int2 scv = seg[node];
        base = __builtin_amdgcn_readfirstlane(scv.x);
        pc   = __builtin_amdgcn_readfirstlane(scv.y);
    }

    float a0 = 0.f, a1 = 0.f, a2 = 0.f, a3 = 0.f;
    float a4 = 0.f, a5 = 0.f, a6 = 0.f, a7 = 0.f;
    agg_core(hw4, sorted_src, base, pc, g, c, a0, a1, a2, a3, a4, a5, a6, a7);

    if (lane < 8) {
        float4 bv0 = *(const float4*)(bias + 8 * c);
        float4 bv1 = *(const float4*)(bias + 8 * c + 4);
        a0 += bv0.x; a1 += bv0.y; a2 += bv0.z; a3 += bv0.w;
        a4 += bv1.x; a5 += bv1.y; a6 += bv1.z; a7 += bv1.w;
        uint4 o;
        o.x = (uint_t)f2bf(fmaxf(a0, 0.f)) | ((uint_t)f2bf(fmaxf(a1, 0.f)) << 16);
        o.y = (uint_t)f2bf(fmaxf(a2, 0.f)) | ((uint_t)f2bf(fmaxf(a3, 0.f)) << 16);
        o.z = (uint_t)f2bf(fmaxf(a4, 0.f)) | ((uint_t)f2bf(fmaxf(a5, 0.f)) << 16);
        o.w = (uint_t)f2bf(fmaxf(a6, 0.f)) | ((uint_t)f2bf(fmaxf(a7, 0.f)) << 16);
        *(uint4*)&Hs[wv * 72 + c * 8] = o;
    }
    __syncthreads();

    if (wv == 0) {
        const int l15  = lane & 15;
        const int quad = lane >> 4;

        short8_t bfrag[4][2];
        #pragma unroll
        for (int nt = 0; nt < 4; ++nt)
            #pragma unroll
            for (int kc = 0; kc < 2; ++kc)
                bfrag[nt][kc] = *(const short8_t*)(Wt + (size_t)(nt * 16 + l15) * 64 + kc * 32 + quad * 8);

        short8_t afr[2];
        #pragma unroll
        for (int kc = 0; kc < 2; ++kc)
            afr[kc] = (l15 < 4) ? *(const short8_t*)&Hs[l15 * 72 + kc * 32 + quad * 8]
                                : (short8_t)0;

        float4_t acc[4];
        #pragma unroll
        for (int nt = 0; nt < 4; ++nt) acc[nt] = (float4_t)0.f;
        #pragma unroll
        for (int kc = 0; kc < 2; ++kc)
            #pragma unroll
            for (int nt = 0; nt < 4; ++nt)
                acc[nt] = __builtin_amdgcn_mfma_f32_16x16x32_bf16(afr[kc], bfrag[nt][kc], acc[nt], 0, 0, 0);

        if (quad == 0) {
            #pragma unroll
            for (int r = 0; r < 4; ++r) {
                int nd = blockIdx.x * 4 + r;
                if (nd < N) {
                    #pragma unroll
                    for (int nt = 0; nt < 4; ++nt)
                        outb[(size_t)nd * CH + nt * 16 + l15] = f2bf(acc[nt][r]);
                }
            }
        }
    }
}

// ---------------- final aggregate (layer 3): + bias, f32 out ----------------
__global__ __launch_bounds__(256) void aggregate_final(
    const ushort_t* __restrict__ hwb, const int* __restrict__ sorted_src,
    const int2* __restrict__ seg, const float* __restrict__ bias,
    float* __restrict__ outf, int N)
{
    const int t    = threadIdx.x;
    const int lane = t & 63;
    const int node = blockIdx.x * 4 + (t >> 6);
    if (node >= N) return;

    int2 scv  = seg[node];
    int  base = __builtin_amdgcn_readfirstlane(scv.x);
    int  pc   = __builtin_amdgcn_readfirstlane(scv.y);

    const int g = lane >> 3;
    const int c = lane & 7;
    const uint4* hw4 = (const uint4*)hwb;

    float a0 = 0.f, a1 = 0.f, a2 = 0.f, a3 = 0.f;
    float a4 = 0.f, a5 = 0.f, a6 = 0.f, a7 = 0.f;
    agg_core(hw4, sorted_src, base, pc, g, c, a0, a1, a2, a3, a4, a5, a6, a7);

    if (lane < 8) {
        float4 bv0 = *(const float4*)(bias + 8 * c);
        float4 bv1 = *(const float4*)(bias + 8 * c + 4);
        a0 += bv0.x; a1 += bv0.y; a2 += bv0.z; a3 += bv0.w;
        a4 += bv1.x; a5 += bv1.y; a6 += bv1.z; a7 += bv1.w;
        *(float4*)(outf + (size_t)node * CH + 8 * c)     = make_float4(a0, a1, a2, a3);
        *(float4*)(outf + (size_t)node * CH + 8 * c + 4) = make_float4(a4, a5, a6, a7);
    }
}

extern "C" void kernel_launch(void* const* d_in, const int* in_sizes, int n_in,
                              void* d_out, int out_size, void* d_ws, size_t ws_size,
                              hipStream_t stream) {
    const float* x    = (const float*)d_in[0];
    const int*   esrc = (const int*)  d_in[1];
    const int*   edst = (const int*)  d_in[2];
    const float* W1   = (const float*)d_in[3];
    const float* b1   = (const float*)d_in[4];
    const float* W2   = (const float*)d_in[5];
    const float* b2   = (const float*)d_in[6];
    const float* W3   = (const float*)d_in[7];
    const float* b3   = (const float*)d_in[8];
    float* out = (float*)d_out;

    const int N  = in_sizes[0] / 128;
    const int E  = in_sizes[1];
    const int NC = (N + CNODES - 1) / CNODES;    // 49 for N=100000

    // workspace layout (~45 MB)
    char* ws = (char*)d_ws;
    ushort_t* hwbA  = (ushort_t*)ws; ws += (size_t)(N + 1) * CH * 2;  // buffer A (+ zero row)
    ushort_t* hwbB  = (ushort_t*)ws; ws += (size_t)(N + 1) * CH * 2;  // buffer B (+ zero row)
    int* bucketed   = (int*)ws;      ws += (size_t)NC * CSTRIDE * 4;  // 7.2 MB
    int* sorted_src = (int*)ws;      ws += (size_t)NC * OSTRIDE * 4;  // 10.4 MB
    int2* seg       = (int2*)ws;     ws += (size_t)N * 8;
    ws = (char*)(((uintptr_t)ws + 63) & ~(uintptr_t)63);
    int* cursor     = (int*)ws;      ws += (size_t)NC_MAX * CUR_PAD * 4;
    ws = (char*)(((uintptr_t)ws + 15) & ~(uintptr_t)15);
    ushort_t* Wt1   = (ushort_t*)ws; ws += (size_t)CH * 128 * 2;
    ushort_t* Wt2   = (ushort_t*)ws; ws += (size_t)CH * 64 * 2;
    ushort_t* Wt3   = (ushort_t*)ws; ws += (size_t)CH * 64 * 2;

    dim3 blk(256);
    int gemmGrid = (N + 1 + 127) / 128;          // covers zero row at index N
    int aggGrid  = (N + 3) / 4;                  // 4 nodes per block, 1 per wave
    int scatGrid = (E + SCAT_CHUNK - 1) / SCAT_CHUNK;

    // ---- prep: weight transposes + coarse cursors + B zero-row (1 dispatch) ----
    prep_kernel<<<4, blk, 0, stream>>>(W1, W2, W3, Wt1, Wt2, Wt3, cursor,
                                       hwbB + (size_t)N * CH);

    // ---- layer-1 GEMM (x @ W1 -> A) fused with coarse scatter (pass A) ----
    gemm1_scat<<<gemmGrid + scatGrid, blk, 0, stream>>>(
        x, Wt1, hwbA, N, esrc, edst, cursor, bucketed, E, gemmGrid);

    // ---- pass B: per-coarse-bucket node sort -> padded segments ----
    node_sort2<<<NC, dim3(1024), 0, stream>>>(bucketed, cursor, sorted_src, seg, N, N /*zero row*/);

    // ---- layer 1 aggregate + relu + @W2 -> B ----
    agg_gemm<<<aggGrid, blk, 0, stream>>>(hwbA, sorted_src, seg, b1, Wt2, hwbB, N);
    // ---- layer 2 aggregate + relu + @W3 -> A ----
    agg_gemm<<<aggGrid, blk, 0, stream>>>(hwbB, sorted_src, seg, b2, Wt3, hwbA, N);
    // ---- layer 3 aggregate -> out (f32) ----
    aggregate_final<<<aggGrid, blk, 0, stream>>>(hwbA, sorted_src, seg, b3, out, N);
}